// Round 18
// baseline (29.739 us; speedup 1.0000x reference)
//
#include <hip/hip_runtime.h>

// CGP coupler, single/duo/quad packed, b128 4-row half-wave geometry.
//
// Structure (validated R3-R16): runs of 32 entries = segments
//   out[:, 32*ob:32*ob+32] += cg * x1[:, a:a+32] * x2[:, b:b+32]
// nseg ~ 580, nob = 280, per-ob counts c in 0..7 (avg ~2), a,b 32-aligned.
//
// R16 -> R17: grid was 256 = 1 block/CU -> no co-resident block to hide
// staging/barrier/store latency. Now ROWS=4, 512 thr (8 waves), grid 512,
// 32 KB LDS -> 2 blocks/CU. Each HALF-WAVE owns its own descriptor
// (lane = half x row(4) x f4group(8)); desc pairs arrive via one wide
// uniform load + per-half cndmask selects. Same slot packing as R16:
//   c<=1 single | c==2 duo | 3<=c<=4 quad (exclusive) | c>=5 shared+atomic.

#define IN_DIM  1024
#define ROWS    4
#define NOBCAP  512
#define SKIP_OB 511u

// ---- prep (1 block, 1024 thr): count -> packed u64 shuffle scan -> fill ----
__global__ __launch_bounds__(1024) void prep_kernel(
    const int* __restrict__ r1, const int* __restrict__ r2,
    const int* __restrict__ ro, const float* __restrict__ cg,
    int nseg, int nob,
    uint2* __restrict__ qdesc, uint2* __restrict__ ddesc, uint2* __restrict__ sdesc,
    int* __restrict__ zlist, int* __restrict__ hdr)
{
    __shared__ int cntS[NOBCAP], rankS[NOBCAP];
    __shared__ int qoffS[NOBCAP], doffS[NOBCAP], soffS[NOBCAP];
    __shared__ unsigned long long wsumS[8], woffS[8];
    const int t = threadIdx.x;

    if (t < NOBCAP) { cntS[t] = 0; rankS[t] = 0; }
    __syncthreads();

    for (int s = t; s < nseg; s += 1024)
        atomicAdd(&cntS[ro[s << 5] >> 5], 1);
    __syncthreads();

    // packed per-ob: q<<48 | duo<<32 | single<<16 | shared ; totals << 65536
    int c = 0;
    unsigned long long pv = 0ull;
    if (t < NOBCAP) {
        c = (t < nob) ? cntS[t] : 0;
        unsigned long long q = 0, df = 0, sf = 0, zf = 0;
        if (t < nob) {
            if (c == 2)      df = 1;
            else if (c <= 1) sf = 1;
            else { q = (unsigned long long)((c + 3) >> 2); if (c > 4) zf = 1; }
        }
        pv = (q << 48) | (df << 32) | (sf << 16) | zf;
    }
    const int lane = t & 63;
    const int wid  = t >> 6;
    #pragma unroll
    for (int off = 1; off < 64; off <<= 1) {
        const unsigned long long n = __shfl_up(pv, off, 64);
        if (lane >= off) pv += n;
    }
    if (t < NOBCAP && lane == 63) wsumS[wid] = pv;
    __syncthreads();
    if (t < 8) {
        unsigned long long v = wsumS[t];
        const unsigned long long self = v;
        #pragma unroll
        for (int off = 1; off < 8; off <<= 1) {
            const unsigned long long n = __shfl_up(v, off, 64);
            if (t >= off) v += n;
        }
        woffS[t] = v - self;
    }
    __syncthreads();

    if (t < NOBCAP) {
        const unsigned long long incl = pv + woffS[wid];
        const int qi = (int)(incl >> 48);
        const int di = (int)((incl >> 32) & 0xFFFFull);
        const int si = (int)((incl >> 16) & 0xFFFFull);
        const int zi = (int)(incl & 0xFFFFull);
        if (t < nob) {
            if (c == 2) {
                doffS[t] = di - 1;
            } else if (c <= 1) {
                soffS[t] = si - 1;
                if (c == 0)
                    sdesc[si - 1] = make_uint2(((unsigned int)t << 20) | 0x80000000u, 0u);
            } else {
                const int qn = (c + 3) >> 2;
                const int qb = qi - qn;
                qoffS[t] = qb;
                const unsigned int fl = (c > 4) ? 0u : 0x80000000u;
                if (c > 4) zlist[zi - 1] = t;
                const unsigned int pd = ((unsigned int)t << 20) | fl;
                for (int j = (qb << 2) + c; j < ((qb + qn) << 2); ++j)
                    qdesc[j] = make_uint2(pd, 0u);
            }
        }
        if (t == NOBCAP - 1) {
            const int nq = qi, nd = di, ns = si;
            const int nqPad = (nq + 15) & ~15;   // 8 waves x 2 quads/iter
            const int ndPad = (nd + 31) & ~31;   // 8 waves x 4 duos/iter
            const int nsPad = (ns + 63) & ~63;   // 8 waves x 8 singles/iter
            const uint2 dummy = make_uint2(SKIP_OB << 20, 0u);
            for (int j = (nq << 2); j < (nqPad << 2); ++j) qdesc[j] = dummy;
            for (int j = (nd << 1); j < (ndPad << 1); ++j) ddesc[j] = dummy;
            for (int j = ns;        j < nsPad;        ++j) sdesc[j] = dummy;
            hdr[0] = nqPad; hdr[1] = zi; hdr[2] = ndPad; hdr[3] = nsPad;
        }
    }
    __syncthreads();

    for (int s = t; s < nseg; s += 1024) {
        const int k  = s << 5;
        const int ob = ro[k] >> 5;
        const int cc = cntS[ob];
        const int rk = atomicAdd(&rankS[ob], 1);
        const unsigned int fl = (cc > 4) ? 0u : 0x80000000u;
        const uint2 v = make_uint2((unsigned int)r1[k] | ((unsigned int)r2[k] << 10)
                                   | ((unsigned int)ob << 20) | fl,
                                   __float_as_uint(cg[k]));
        if (cc == 2)      ddesc[(doffS[ob] << 1) + rk] = v;
        else if (cc == 1) sdesc[soffS[ob]] = v;
        else              qdesc[(qoffS[ob] << 2) + rk] = v;
    }
}

__device__ __forceinline__ void accum4(float4& acc, unsigned int dx, unsigned int dc,
                                       const float* xs1, const float* xs2)
{
    const float  c = __uint_as_float(dc);
    const float4 u = *reinterpret_cast<const float4*>(xs1 + (dx & 1023u));
    const float4 v = *reinterpret_cast<const float4*>(xs2 + ((dx >> 10) & 1023u));
    acc.x = fmaf(c, u.x * v.x, acc.x);
    acc.y = fmaf(c, u.y * v.y, acc.y);
    acc.z = fmaf(c, u.z * v.z, acc.z);
    acc.w = fmaf(c, u.w * v.w, acc.w);
}

__device__ __forceinline__ void terminal(float* orow, unsigned int hx, float4 acc)
{
    const int ob = (int)((hx >> 20) & 511u);
    if (ob == (int)SKIP_OB) return;
    float* p = orow + (ob << 5);
    if (hx >> 31) {
        *reinterpret_cast<float4*>(p) = acc;
    } else {
        unsafeAtomicAdd(p,     acc.x);
        unsafeAtomicAdd(p + 1, acc.y);
        unsafeAtomicAdd(p + 2, acc.z);
        unsafeAtomicAdd(p + 3, acc.w);
    }
}

// ---- main: block = 4 rows, 8 waves; lane = half x row(2b) x f4group(3b) ----
__global__ __launch_bounds__(512) void cgp_main(const float* __restrict__ x1,
    const float* __restrict__ x2, const uint2* __restrict__ qdesc,
    const uint2* __restrict__ ddesc, const uint2* __restrict__ sdesc,
    const int* __restrict__ zlist, const int* __restrict__ hdr,
    float* __restrict__ out, int out_dim)
{
    __shared__ float x1s[ROWS * IN_DIM];             // 16 KB
    __shared__ float x2s[ROWS * IN_DIM];             // 16 KB
    const int r0  = blockIdx.x * ROWS;
    const int tid = threadIdx.x;

    {
        const float4* p1 = reinterpret_cast<const float4*>(x1 + (size_t)r0 * IN_DIM);
        const float4* p2 = reinterpret_cast<const float4*>(x2 + (size_t)r0 * IN_DIM);
        float4* s1 = reinterpret_cast<float4*>(x1s);
        float4* s2 = reinterpret_cast<float4*>(x2s);
        #pragma unroll
        for (int j = tid; j < (ROWS * IN_DIM) >> 2; j += 512) { s1[j] = p1[j]; s2[j] = p2[j]; }
    }
    const int nz = hdr[1];
    for (int i = tid; i < (nz << 5); i += 512) {     // pre-zero shared obs
        const int ob = zlist[i >> 5];
        const int ch = i & 31;
        float* p = out + (size_t)r0 * out_dim + (ob << 5) + ch;
        #pragma unroll
        for (int j = 0; j < ROWS; ++j) p[j * out_dim] = 0.f;
    }
    __syncthreads();

    const int w  = tid >> 6;                         // wave 0..7
    const int ln = tid & 63;
    const bool hi = (ln >> 5) != 0;                  // half-wave select
    const int hl = ln & 31;
    const int rr = hl >> 3;                          // row 0..3
    const int tt = hl & 7;                           // float4-channel group
    const float* xs1 = x1s + rr * IN_DIM + (tt << 2);
    const float* xs2 = x2s + rr * IN_DIM + (tt << 2);
    float* orow = out + (size_t)(r0 + rr) * out_dim + (tt << 2);

    // ---- quad loop: 2 quads per wave-iter (one per half) ----
    {
        const int qpw = hdr[0] >> 3;                 // quads per wave (even)
        const uint2* qd = qdesc + ((size_t)(w * qpw) << 2);
        for (int i = 0; i < qpw; i += 2, qd += 8) {
            const uint4 A0 = *reinterpret_cast<const uint4*>(qd);
            const uint4 B0 = *reinterpret_cast<const uint4*>(qd + 2);
            const uint4 A1 = *reinterpret_cast<const uint4*>(qd + 4);
            const uint4 B1 = *reinterpret_cast<const uint4*>(qd + 6);
            const uint4 A  = hi ? A1 : A0;
            const uint4 Bq = hi ? B1 : B0;
            float4 acc = make_float4(0.f, 0.f, 0.f, 0.f);
            accum4(acc, A.x,  A.y,  xs1, xs2);
            accum4(acc, A.z,  A.w,  xs1, xs2);
            accum4(acc, Bq.x, Bq.y, xs1, xs2);
            accum4(acc, Bq.z, Bq.w, xs1, xs2);
            terminal(orow, A.x, acc);
        }
    }

    // ---- duo loop: 4 duos per wave-iter (a duo-pair per half) ----
    {
        const int dpw = hdr[2] >> 3;                 // duos per wave (mult of 4)
        const uint2* dd = ddesc + ((size_t)(w * dpw) << 1);
        for (int i = 0; i < dpw; i += 4, dd += 8) {
            const uint4 A0 = *reinterpret_cast<const uint4*>(dd);
            const uint4 B0 = *reinterpret_cast<const uint4*>(dd + 2);
            const uint4 A1 = *reinterpret_cast<const uint4*>(dd + 4);
            const uint4 B1 = *reinterpret_cast<const uint4*>(dd + 6);
            const uint4 A  = hi ? A1 : A0;
            const uint4 Bq = hi ? B1 : B0;
            float4 a0 = make_float4(0.f, 0.f, 0.f, 0.f);
            float4 a1 = make_float4(0.f, 0.f, 0.f, 0.f);
            accum4(a0, A.x,  A.y,  xs1, xs2);
            accum4(a0, A.z,  A.w,  xs1, xs2);
            accum4(a1, Bq.x, Bq.y, xs1, xs2);
            accum4(a1, Bq.z, Bq.w, xs1, xs2);
            terminal(orow, A.x,  a0);
            terminal(orow, Bq.x, a1);
        }
    }

    // ---- singles loop: 8 singles per wave-iter (4 per half) ----
    {
        const int spw = hdr[3] >> 3;                 // singles per wave (mult of 8)
        const uint2* sd = sdesc + (size_t)(w * spw);
        for (int i = 0; i < spw; i += 8, sd += 8) {
            const uint4 A0 = *reinterpret_cast<const uint4*>(sd);
            const uint4 B0 = *reinterpret_cast<const uint4*>(sd + 2);
            const uint4 A1 = *reinterpret_cast<const uint4*>(sd + 4);
            const uint4 B1 = *reinterpret_cast<const uint4*>(sd + 6);
            const uint4 A  = hi ? A1 : A0;
            const uint4 Bq = hi ? B1 : B0;
            float4 a0 = make_float4(0.f, 0.f, 0.f, 0.f);
            float4 a1 = make_float4(0.f, 0.f, 0.f, 0.f);
            float4 a2 = make_float4(0.f, 0.f, 0.f, 0.f);
            float4 a3 = make_float4(0.f, 0.f, 0.f, 0.f);
            accum4(a0, A.x,  A.y,  xs1, xs2);
            accum4(a1, A.z,  A.w,  xs1, xs2);
            accum4(a2, Bq.x, Bq.y, xs1, xs2);
            accum4(a3, Bq.z, Bq.w, xs1, xs2);
            terminal(orow, A.x,  a0);
            terminal(orow, A.z,  a1);
            terminal(orow, Bq.x, a2);
            terminal(orow, Bq.z, a3);
        }
    }
}

extern "C" void kernel_launch(void* const* d_in, const int* in_sizes, int n_in,
                              void* d_out, int out_size, void* d_ws, size_t ws_size,
                              hipStream_t stream)
{
    const float* x1 = (const float*)d_in[0];
    const float* x2 = (const float*)d_in[1];
    const float* cg = (const float*)d_in[2];
    const int*   r1 = (const int*)d_in[3];
    const int*   r2 = (const int*)d_in[4];
    const int*   ro = (const int*)d_in[5];
    float* out = (float*)d_out;

    const int B       = in_sizes[0] / IN_DIM;   // 2048
    const int out_dim = out_size / B;           // 8960
    const int K       = in_sizes[2];
    const int nseg    = K >> 5;                 // ~580
    const int nob     = out_dim >> 5;           // 280
    const int qcap    = nob + (nseg >> 2) + 32;
    const int dcap    = nob + 48;
    const int scap    = nob + 80;

    auto align16 = [](size_t v) { return (v + 15) & ~(size_t)15; };
    char* ws = (char*)d_ws;
    uint2* qdesc = (uint2*)ws;  ws += align16((size_t)qcap * 4 * sizeof(uint2));
    uint2* ddesc = (uint2*)ws;  ws += align16((size_t)dcap * 2 * sizeof(uint2));
    uint2* sdesc = (uint2*)ws;  ws += align16((size_t)scap * sizeof(uint2));
    int*   zlist = (int*)ws;    ws += align16((size_t)NOBCAP * sizeof(int));
    int*   hdr   = (int*)ws;

    hipLaunchKernelGGL(prep_kernel, dim3(1), dim3(1024), 0, stream,
                       r1, r2, ro, cg, nseg, nob, qdesc, ddesc, sdesc, zlist, hdr);
    hipLaunchKernelGGL(cgp_main, dim3(B / ROWS), dim3(512), 0, stream,
                       x1, x2, qdesc, ddesc, sdesc, zlist, hdr, out, out_dim);
}

// Round 21
// 29.497 us; speedup vs baseline: 1.0082x; 1.0082x over previous
//
#include <hip/hip_runtime.h>

// CGP coupler, FULLY FUSED single-dispatch form.
//
// Structure (validated R3-R18): runs of 32 entries = segments
//   out[:, 32*ob:32*ob+32] += cg * x1[:, a:a+32] * x2[:, b:b+32]
// nseg ~ 580, nob = 280, per-ob counts c in 0..7 (avg ~2), a,b 32-aligned.
//
// R15-R18 lesson: the gather/store main loop plateaus at ~20-22 us; the
// remaining ~6 us of the 28.7 total is the serial prep dispatch (1 block,
// 255 CUs idle) + inter-dispatch gap. Fix: ONE kernel; every block re-runs
// prep locally into LDS (redundant but cheap: ~1160 L2-hot loads + a
// 512-wide shuffle scan per block), then runs the proven R17 half-wave
// b128 gather loops with descriptors read from LDS (uniform broadcasts).
//   class packing: c<=1 single | c==2 duo | 3<=c<=4 quad | c>=5 shared.
// LDS slot caps audited vs worst-case nseg~600: quads<=988 slots,
// duos<=591, singles<=320, zlist<=120 -> all within caps; 58.6 KB total.

#define IN_DIM  1024
#define ROWS    4
#define NOBCAP  512
#define SKIP_OB 511u
#define QSLOTS  1024   // quad desc slots cap (8 KB)
#define DSLOTS  640    // duo desc slots cap (5 KB)
#define SSLOTS  384    // single desc slots cap (3 KB)

__device__ __forceinline__ void accum4(float4& acc, unsigned int dx, unsigned int dc,
                                       const float* xs1, const float* xs2)
{
    const float  c = __uint_as_float(dc);
    const float4 u = *reinterpret_cast<const float4*>(xs1 + (dx & 1023u));
    const float4 v = *reinterpret_cast<const float4*>(xs2 + ((dx >> 10) & 1023u));
    acc.x = fmaf(c, u.x * v.x, acc.x);
    acc.y = fmaf(c, u.y * v.y, acc.y);
    acc.z = fmaf(c, u.z * v.z, acc.z);
    acc.w = fmaf(c, u.w * v.w, acc.w);
}

__device__ __forceinline__ void terminal(float* orow, unsigned int hx, float4 acc)
{
    const int ob = (int)((hx >> 20) & 511u);
    if (ob == (int)SKIP_OB) return;                  // tail pad: no output
    float* p = orow + (ob << 5);
    if (hx >> 31) {
        *reinterpret_cast<float4*>(p) = acc;         // exclusive: plain store
    } else {                                         // shared: native fadd
        unsafeAtomicAdd(p,     acc.x);
        unsafeAtomicAdd(p + 1, acc.y);
        unsafeAtomicAdd(p + 2, acc.z);
        unsafeAtomicAdd(p + 3, acc.w);
    }
}

__global__ __launch_bounds__(512) void cgp_fused(
    const float* __restrict__ x1, const float* __restrict__ x2,
    const int* __restrict__ r1, const int* __restrict__ r2,
    const int* __restrict__ ro, const float* __restrict__ cg,
    int nseg, int nob, float* __restrict__ out, int out_dim)
{
    __shared__ float x1s[ROWS * IN_DIM];             // 16 KB
    __shared__ float x2s[ROWS * IN_DIM];             // 16 KB
    __shared__ uint2 qdescL[QSLOTS];                 // 8 KB
    __shared__ uint2 ddescL[DSLOTS];                 // 5 KB
    __shared__ uint2 sdescL[SSLOTS];                 // 3 KB
    __shared__ int cntS[NOBCAP], rankS[NOBCAP];      // 4 KB
    __shared__ int qoffS[NOBCAP], doffS[NOBCAP], soffS[NOBCAP];   // 6 KB
    __shared__ unsigned long long wsumS[8], woffS[8];
    __shared__ int zlistL[128];
    __shared__ int hdrL[4];

    const int r0  = blockIdx.x * ROWS;
    const int t   = threadIdx.x;                     // 0..511

    // ---- stage input rows (independent of prep; loads fly during prep) ----
    {
        const float4* p1 = reinterpret_cast<const float4*>(x1 + (size_t)r0 * IN_DIM);
        const float4* p2 = reinterpret_cast<const float4*>(x2 + (size_t)r0 * IN_DIM);
        float4* s1 = reinterpret_cast<float4*>(x1s);
        float4* s2 = reinterpret_cast<float4*>(x2s);
        #pragma unroll
        for (int j = t; j < (ROWS * IN_DIM) >> 2; j += 512) { s1[j] = p1[j]; s2[j] = p2[j]; }
    }

    // ---- local prep phase 1: zero + count ----
    cntS[t] = 0; rankS[t] = 0;
    __syncthreads();
    for (int s = t; s < nseg; s += 512)
        atomicAdd(&cntS[ro[s << 5] >> 5], 1);
    __syncthreads();

    // ---- phase 2: packed u64 shuffle scan (q<<48 | duo<<32 | sgl<<16 | shr) ----
    const int c = (t < nob) ? cntS[t] : 0;
    unsigned long long pv;
    {
        unsigned long long q = 0, df = 0, sf = 0, zf = 0;
        if (t < nob) {
            if (c == 2)      df = 1;
            else if (c <= 1) sf = 1;
            else { q = (unsigned long long)((c + 3) >> 2); if (c > 4) zf = 1; }
        }
        pv = (q << 48) | (df << 32) | (sf << 16) | zf;
    }
    const int lane = t & 63;
    const int wid  = t >> 6;
    #pragma unroll
    for (int off = 1; off < 64; off <<= 1) {
        const unsigned long long n = __shfl_up(pv, off, 64);
        if (lane >= off) pv += n;
    }
    if (lane == 63) wsumS[wid] = pv;
    __syncthreads();
    if (t < 8) {
        unsigned long long v = wsumS[t];
        const unsigned long long self = v;
        #pragma unroll
        for (int off = 1; off < 8; off <<= 1) {
            const unsigned long long n = __shfl_up(v, off, 64);
            if (t >= off) v += n;
        }
        woffS[t] = v - self;
    }
    __syncthreads();

    // ---- phase 3: per-ob offsets, pads, zlist, hdr ----
    {
        const unsigned long long incl = pv + woffS[wid];
        const int qi = (int)(incl >> 48);
        const int di = (int)((incl >> 32) & 0xFFFFull);
        const int si = (int)((incl >> 16) & 0xFFFFull);
        const int zi = (int)(incl & 0xFFFFull);
        if (t < nob) {
            if (c == 2) {
                doffS[t] = di - 1;
            } else if (c <= 1) {
                soffS[t] = si - 1;
                if (c == 0)
                    sdescL[si - 1] = make_uint2(((unsigned int)t << 20) | 0x80000000u, 0u);
            } else {
                const int qn = (c + 3) >> 2;
                const int qb = qi - qn;
                qoffS[t] = qb;
                const unsigned int fl = (c > 4) ? 0u : 0x80000000u;
                if (c > 4) zlistL[zi - 1] = t;
                const unsigned int pd = ((unsigned int)t << 20) | fl;
                for (int j = (qb << 2) + c; j < ((qb + qn) << 2); ++j)
                    qdescL[j] = make_uint2(pd, 0u);
            }
        }
        if (t == NOBCAP - 1) {
            const int nq = qi, nd = di, ns = si;
            const int nqPad = (nq + 15) & ~15;       // 8 waves x 2 quads/iter
            const int ndPad = (nd + 31) & ~31;       // 8 waves x 4 duos/iter
            const int nsPad = (ns + 63) & ~63;       // 8 waves x 8 singles/iter
            const uint2 dummy = make_uint2(SKIP_OB << 20, 0u);
            for (int j = (nq << 2); j < (nqPad << 2); ++j) qdescL[j] = dummy;
            for (int j = (nd << 1); j < (ndPad << 1); ++j) ddescL[j] = dummy;
            for (int j = ns;        j < nsPad;        ++j) sdescL[j] = dummy;
            hdrL[0] = nqPad; hdrL[1] = zi; hdrL[2] = ndPad; hdrL[3] = nsPad;
        }
    }
    __syncthreads();

    // ---- phase 4: fill real descriptors into LDS ----
    for (int s = t; s < nseg; s += 512) {
        const int k  = s << 5;
        const int ob = ro[k] >> 5;
        const int cc = cntS[ob];
        const int rk = atomicAdd(&rankS[ob], 1);
        const unsigned int fl = (cc > 4) ? 0u : 0x80000000u;
        const uint2 v = make_uint2((unsigned int)r1[k] | ((unsigned int)r2[k] << 10)
                                   | ((unsigned int)ob << 20) | fl,
                                   __float_as_uint(cg[k]));
        if (cc == 2)      ddescL[(doffS[ob] << 1) + rk] = v;
        else if (cc == 1) sdescL[soffS[ob]] = v;
        else              qdescL[(qoffS[ob] << 2) + rk] = v;
    }
    __syncthreads();

    // ---- pre-zero shared obs of our rows ----
    const int nz = hdrL[1];
    for (int i = t; i < (nz << 5); i += 512) {
        const int ob = zlistL[i >> 5];
        const int ch = i & 31;
        float* p = out + (size_t)r0 * out_dim + (ob << 5) + ch;
        #pragma unroll
        for (int j = 0; j < ROWS; ++j) p[j * out_dim] = 0.f;
    }
    __syncthreads();

    // ---- gather/store loops (R17 half-wave b128 geometry) ----
    const int w  = t >> 6;                           // wave 0..7
    const int ln = t & 63;
    const bool hi = (ln >> 5) != 0;                  // half-wave select
    const int hl = ln & 31;
    const int rr = hl >> 3;                          // row 0..3
    const int tt = hl & 7;                           // float4-channel group
    const float* xs1 = x1s + rr * IN_DIM + (tt << 2);
    const float* xs2 = x2s + rr * IN_DIM + (tt << 2);
    float* orow = out + (size_t)(r0 + rr) * out_dim + (tt << 2);

    // quad loop: 2 quads per wave-iter (one per half)
    {
        const int qpw = hdrL[0] >> 3;
        const uint2* qd = qdescL + ((size_t)(w * qpw) << 2);
        for (int i = 0; i < qpw; i += 2, qd += 8) {
            const uint4 A0 = *reinterpret_cast<const uint4*>(qd);
            const uint4 B0 = *reinterpret_cast<const uint4*>(qd + 2);
            const uint4 A1 = *reinterpret_cast<const uint4*>(qd + 4);
            const uint4 B1 = *reinterpret_cast<const uint4*>(qd + 6);
            const uint4 A  = hi ? A1 : A0;
            const uint4 Bq = hi ? B1 : B0;
            float4 acc = make_float4(0.f, 0.f, 0.f, 0.f);
            accum4(acc, A.x,  A.y,  xs1, xs2);
            accum4(acc, A.z,  A.w,  xs1, xs2);
            accum4(acc, Bq.x, Bq.y, xs1, xs2);
            accum4(acc, Bq.z, Bq.w, xs1, xs2);
            terminal(orow, A.x, acc);
        }
    }
    // duo loop: 4 duos per wave-iter (a duo-pair per half)
    {
        const int dpw = hdrL[2] >> 3;
        const uint2* dd = ddescL + ((size_t)(w * dpw) << 1);
        for (int i = 0; i < dpw; i += 4, dd += 8) {
            const uint4 A0 = *reinterpret_cast<const uint4*>(dd);
            const uint4 B0 = *reinterpret_cast<const uint4*>(dd + 2);
            const uint4 A1 = *reinterpret_cast<const uint4*>(dd + 4);
            const uint4 B1 = *reinterpret_cast<const uint4*>(dd + 6);
            const uint4 A  = hi ? A1 : A0;
            const uint4 Bq = hi ? B1 : B0;
            float4 a0 = make_float4(0.f, 0.f, 0.f, 0.f);
            float4 a1 = make_float4(0.f, 0.f, 0.f, 0.f);
            accum4(a0, A.x,  A.y,  xs1, xs2);
            accum4(a0, A.z,  A.w,  xs1, xs2);
            accum4(a1, Bq.x, Bq.y, xs1, xs2);
            accum4(a1, Bq.z, Bq.w, xs1, xs2);
            terminal(orow, A.x,  a0);
            terminal(orow, Bq.x, a1);
        }
    }
    // singles loop: 8 singles per wave-iter (4 per half)
    {
        const int spw = hdrL[3] >> 3;
        const uint2* sd = sdescL + (size_t)(w * spw);
        for (int i = 0; i < spw; i += 8, sd += 8) {
            const uint4 A0 = *reinterpret_cast<const uint4*>(sd);
            const uint4 B0 = *reinterpret_cast<const uint4*>(sd + 2);
            const uint4 A1 = *reinterpret_cast<const uint4*>(sd + 4);
            const uint4 B1 = *reinterpret_cast<const uint4*>(sd + 6);
            const uint4 A  = hi ? A1 : A0;
            const uint4 Bq = hi ? B1 : B0;
            float4 a0 = make_float4(0.f, 0.f, 0.f, 0.f);
            float4 a1 = make_float4(0.f, 0.f, 0.f, 0.f);
            float4 a2 = make_float4(0.f, 0.f, 0.f, 0.f);
            float4 a3 = make_float4(0.f, 0.f, 0.f, 0.f);
            accum4(a0, A.x,  A.y,  xs1, xs2);
            accum4(a1, A.z,  A.w,  xs1, xs2);
            accum4(a2, Bq.x, Bq.y, xs1, xs2);
            accum4(a3, Bq.z, Bq.w, xs1, xs2);
            terminal(orow, A.x,  a0);
            terminal(orow, A.z,  a1);
            terminal(orow, Bq.x, a2);
            terminal(orow, Bq.z, a3);
        }
    }
}

extern "C" void kernel_launch(void* const* d_in, const int* in_sizes, int n_in,
                              void* d_out, int out_size, void* d_ws, size_t ws_size,
                              hipStream_t stream)
{
    const float* x1 = (const float*)d_in[0];
    const float* x2 = (const float*)d_in[1];
    const float* cg = (const float*)d_in[2];
    const int*   r1 = (const int*)d_in[3];
    const int*   r2 = (const int*)d_in[4];
    const int*   ro = (const int*)d_in[5];
    float* out = (float*)d_out;

    const int B       = in_sizes[0] / IN_DIM;   // 2048
    const int out_dim = out_size / B;           // 8960
    const int K       = in_sizes[2];
    const int nseg    = K >> 5;                 // ~580
    const int nob     = out_dim >> 5;           // 280

    hipLaunchKernelGGL(cgp_fused, dim3(B / ROWS), dim3(512), 0, stream,
                       x1, x2, r1, r2, ro, cg, nseg, nob, out, out_dim);
}

// Round 22
// 28.662 us; speedup vs baseline: 1.0376x; 1.0291x over previous
//
#include <hip/hip_runtime.h>

// CGP coupler, duo+quad packed, b128 8-row geometry + PACKED-FP32 math.
//
// Structure (validated R3-R21): runs of 32 entries = segments
//   out[:, 32*ob:32*ob+32] += cg * x1[:, a:a+32] * x2[:, b:b+32]
// nseg ~ 580, nob = 280, per-ob counts c in 0..7 (avg ~2), a,b 32-aligned.
//
// R21 lesson: prep/launch overhead is NOT the residual (fusion was null);
// across 7 variants the plateau is in-loop. Largest non-HBM term by
// arithmetic: VALU issue (~8-10 us/CU). R22 = R15 (best, 28.7 us) with
// accum4 rewritten on ext_vector float2 so clang emits v_pk_mul_f32 /
// v_pk_fma_f32 (CDNA packed fp32): 8 math instr/slot -> 4. Loads remain
// ds_read_b128; stores remain dwordx4.

#define IN_DIM  1024
#define ROWS    8
#define NOBCAP  512
#define SKIP_OB 511u

typedef float f32x2 __attribute__((ext_vector_type(2)));

// ---- prep (1 block, 1024 thr): count -> packed shuffle scan -> fill ----
__global__ __launch_bounds__(1024) void prep_kernel(
    const int* __restrict__ r1, const int* __restrict__ r2,
    const int* __restrict__ ro, const float* __restrict__ cg,
    int nseg, int nob,
    uint2* __restrict__ qdesc, uint2* __restrict__ ddesc,
    int* __restrict__ zlist, int* __restrict__ hdr)
{
    __shared__ int cntS[NOBCAP], rankS[NOBCAP];
    __shared__ int qoffS[NOBCAP], doffS[NOBCAP];
    __shared__ int wsum[8], woff[8];
    const int t = threadIdx.x;

    if (t < NOBCAP) { cntS[t] = 0; rankS[t] = 0; }
    __syncthreads();

    for (int s = t; s < nseg; s += 1024)
        atomicAdd(&cntS[ro[s << 5] >> 5], 1);
    __syncthreads();

    // packed per-ob value: q(quads)<<20 | d(is-duo)<<10 | z(is-shared)
    int c = 0;
    unsigned int pv = 0;
    if (t < NOBCAP) {
        c = (t < nob) ? cntS[t] : 0;
        const int q  = (t < nob && c >= 3) ? ((c + 3) >> 2) : 0;
        const int df = (t < nob && c <= 2) ? 1 : 0;
        const int zf = (t < nob && c > 4) ? 1 : 0;
        pv = ((unsigned int)q << 20) | ((unsigned int)df << 10) | (unsigned int)zf;
    }
    const int lane = t & 63;
    const int wid  = t >> 6;
    #pragma unroll
    for (int off = 1; off < 64; off <<= 1) {
        const unsigned int n = __shfl_up(pv, off, 64);
        if (lane >= off) pv += n;
    }
    if (t < NOBCAP && lane == 63) wsum[wid] = (int)pv;
    __syncthreads();
    if (t < 8) {
        unsigned int v = (unsigned int)wsum[t];
        const unsigned int self = v;
        #pragma unroll
        for (int off = 1; off < 8; off <<= 1) {
            const unsigned int n = __shfl_up(v, off, 64);
            if (t >= off) v += n;
        }
        woff[t] = (int)(v - self);
    }
    __syncthreads();

    if (t < NOBCAP) {
        const unsigned int incl = pv + (unsigned int)woff[wid];
        const int qi = (incl >> 20) & 1023;
        const int di = (incl >> 10) & 1023;
        const int zi = incl & 1023;
        if (t < nob) {
            if (c <= 2) {                                   // duo ob (incl empty)
                const int db = di - 1;
                doffS[t] = db;
                const unsigned int pd = ((unsigned int)t << 20) | 0x80000000u;
                for (int j = (db << 1) + c; j < ((db + 1) << 1); ++j)
                    ddesc[j] = make_uint2(pd, 0u);          // pad: cg=0
            } else {                                        // quad ob
                const int qn = (c + 3) >> 2;
                const int qb = qi - qn;
                qoffS[t] = qb;
                const unsigned int fl = (c > 4) ? 0u : 0x80000000u;
                if (c > 4) zlist[zi - 1] = t;
                const unsigned int pd = ((unsigned int)t << 20) | fl;
                for (int j = (qb << 2) + c; j < ((qb + qn) << 2); ++j)
                    qdesc[j] = make_uint2(pd, 0u);
            }
        }
        if (t == NOBCAP - 1) {
            const int nq = qi, nd = di;
            const int nqPad = (nq + 15) & ~15;              // 16 quads (1/wave)
            const int ndPad = (nd + 31) & ~31;              // 32 duos (1 pair/wave)
            const uint2 dummy = make_uint2(SKIP_OB << 20, 0u);  // terminal skipped
            for (int j = (nq << 2); j < (nqPad << 2); ++j) qdesc[j] = dummy;
            for (int j = (nd << 1); j < (ndPad << 1); ++j) ddesc[j] = dummy;
            hdr[0] = nqPad; hdr[1] = zi; hdr[2] = ndPad;
        }
    }
    __syncthreads();

    for (int s = t; s < nseg; s += 1024) {
        const int k  = s << 5;
        const int ob = ro[k] >> 5;
        const int cc = cntS[ob];
        const int rk = atomicAdd(&rankS[ob], 1);
        const unsigned int fl = (cc > 4) ? 0u : 0x80000000u;
        const uint2 v = make_uint2((unsigned int)r1[k] | ((unsigned int)r2[k] << 10)
                                   | ((unsigned int)ob << 20) | fl,
                                   __float_as_uint(cg[k]));
        if (cc <= 2) ddesc[(doffS[ob] << 1) + rk] = v;
        else         qdesc[(qoffS[ob] << 2) + rk] = v;
    }
}

// packed-fp32 accumulate: ds_read_b128 loads, v_pk_mul/v_pk_fma math
__device__ __forceinline__ void accum4(f32x2& lo, f32x2& hi,
                                       unsigned int dx, unsigned int dc,
                                       const float* xs1, const float* xs2)
{
    const float  c = __uint_as_float(dc);
    const float4 u = *reinterpret_cast<const float4*>(xs1 + (dx & 1023u));
    const float4 v = *reinterpret_cast<const float4*>(xs2 + ((dx >> 10) & 1023u));
    const f32x2 cc  = {c, c};
    const f32x2 u01 = {u.x, u.y}, u23 = {u.z, u.w};
    const f32x2 v01 = {v.x, v.y}, v23 = {v.z, v.w};
    lo += cc * (u01 * v01);      // pk_mul + pk_fma (contract)
    hi += cc * (u23 * v23);
}

__device__ __forceinline__ void terminal(float* orow, unsigned int hx,
                                         f32x2 lo, f32x2 hi)
{
    const int ob = (int)((hx >> 20) & 511u);
    if (ob == (int)SKIP_OB) return;                  // tail pad: no output
    float* p = orow + (ob << 5);
    if (hx >> 31) {
        const float4 st = make_float4(lo.x, lo.y, hi.x, hi.y);
        *reinterpret_cast<float4*>(p) = st;          // exclusive: plain store
    } else {                                         // shared: native fadd
        unsafeAtomicAdd(p,     lo.x);
        unsafeAtomicAdd(p + 1, lo.y);
        unsafeAtomicAdd(p + 2, hi.x);
        unsafeAtomicAdd(p + 3, hi.y);
    }
}

// ---- main: block = 8 rows, 16 waves; lane = row(3b) x float4-group(3b) ----
__global__ __launch_bounds__(1024) void cgp_main(const float* __restrict__ x1,
    const float* __restrict__ x2, const uint2* __restrict__ qdesc,
    const uint2* __restrict__ ddesc, const int* __restrict__ zlist,
    const int* __restrict__ hdr, float* __restrict__ out, int out_dim)
{
    __shared__ float x1s[ROWS * IN_DIM];             // 32 KB
    __shared__ float x2s[ROWS * IN_DIM];             // 32 KB
    const int r0  = blockIdx.x * ROWS;
    const int tid = threadIdx.x;

    {
        const float4* p1 = reinterpret_cast<const float4*>(x1 + (size_t)r0 * IN_DIM);
        const float4* p2 = reinterpret_cast<const float4*>(x2 + (size_t)r0 * IN_DIM);
        float4* s1 = reinterpret_cast<float4*>(x1s);
        float4* s2 = reinterpret_cast<float4*>(x2s);
        #pragma unroll
        for (int j = tid; j < (ROWS * IN_DIM) >> 2; j += 1024) { s1[j] = p1[j]; s2[j] = p2[j]; }
    }
    const int nz = hdr[1];
    for (int i = tid; i < (nz << 5); i += 1024) {    // pre-zero shared obs
        const int ob = zlist[i >> 5];
        const int ch = i & 31;
        float* p = out + (size_t)r0 * out_dim + (ob << 5) + ch;
        #pragma unroll
        for (int j = 0; j < ROWS; ++j) p[j * out_dim] = 0.f;
    }
    __syncthreads();

    const int w  = tid >> 6;                         // wave 0..15
    const int ln = tid & 63;
    const int rr = ln >> 3;                          // row 0..7
    const int tt = ln & 7;                           // float4-channel group
    const float* xs1 = x1s + rr * IN_DIM + (tt << 2);
    const float* xs2 = x2s + rr * IN_DIM + (tt << 2);
    float* orow = out + (size_t)(r0 + rr) * out_dim + (tt << 2);

    // ---- quad loop (obs with c>=3) ----
    {
        const int qpw = hdr[0] >> 4;                 // quads per wave
        const uint2* qd = qdesc + ((size_t)(w * qpw) << 2);
        #pragma unroll 2
        for (int i = 0; i < qpw; ++i, qd += 4) {
            const uint4 A  = *reinterpret_cast<const uint4*>(qd);
            const uint4 Bq = *reinterpret_cast<const uint4*>(qd + 2);
            f32x2 lo = {0.f, 0.f}, hi = {0.f, 0.f};
            accum4(lo, hi, A.x,  A.y,  xs1, xs2);
            accum4(lo, hi, A.z,  A.w,  xs1, xs2);
            accum4(lo, hi, Bq.x, Bq.y, xs1, xs2);
            accum4(lo, hi, Bq.z, Bq.w, xs1, xs2);
            terminal(orow, A.x, lo, hi);
        }
    }

    // ---- duo-pair loop (obs with c<=2; two independent terminals) ----
    {
        const int ppw = hdr[2] >> 5;                 // duo-pairs per wave
        const uint2* dd = ddesc + ((size_t)(w * ppw) << 2);
        #pragma unroll 2
        for (int i = 0; i < ppw; ++i, dd += 4) {
            const uint4 A  = *reinterpret_cast<const uint4*>(dd);
            const uint4 Bq = *reinterpret_cast<const uint4*>(dd + 2);
            f32x2 l0 = {0.f, 0.f}, h0 = {0.f, 0.f};
            f32x2 l1 = {0.f, 0.f}, h1 = {0.f, 0.f};
            accum4(l0, h0, A.x,  A.y,  xs1, xs2);
            accum4(l0, h0, A.z,  A.w,  xs1, xs2);
            accum4(l1, h1, Bq.x, Bq.y, xs1, xs2);
            accum4(l1, h1, Bq.z, Bq.w, xs1, xs2);
            terminal(orow, A.x,  l0, h0);
            terminal(orow, Bq.x, l1, h1);
        }
    }
}

extern "C" void kernel_launch(void* const* d_in, const int* in_sizes, int n_in,
                              void* d_out, int out_size, void* d_ws, size_t ws_size,
                              hipStream_t stream)
{
    const float* x1 = (const float*)d_in[0];
    const float* x2 = (const float*)d_in[1];
    const float* cg = (const float*)d_in[2];
    const int*   r1 = (const int*)d_in[3];
    const int*   r2 = (const int*)d_in[4];
    const int*   ro = (const int*)d_in[5];
    float* out = (float*)d_out;

    const int B       = in_sizes[0] / IN_DIM;   // 2048
    const int out_dim = out_size / B;           // 8960
    const int K       = in_sizes[2];
    const int nseg    = K >> 5;                 // ~580
    const int nob     = out_dim >> 5;           // 280
    const int qcap    = nob + (nseg >> 2) + 32; // quad capacity upper bound
    const int dcap    = nob + 48;               // duo capacity upper bound

    auto align16 = [](size_t v) { return (v + 15) & ~(size_t)15; };
    char* ws = (char*)d_ws;
    uint2* qdesc = (uint2*)ws;  ws += align16((size_t)qcap * 4 * sizeof(uint2));
    uint2* ddesc = (uint2*)ws;  ws += align16((size_t)dcap * 2 * sizeof(uint2));
    int*   zlist = (int*)ws;    ws += align16((size_t)NOBCAP * sizeof(int));
    int*   hdr   = (int*)ws;

    hipLaunchKernelGGL(prep_kernel, dim3(1), dim3(1024), 0, stream,
                       r1, r2, ro, cg, nseg, nob, qdesc, ddesc, zlist, hdr);
    hipLaunchKernelGGL(cgp_main, dim3(B / ROWS), dim3(1024), 0, stream,
                       x1, x2, qdesc, ddesc, zlist, hdr, out, out_dim);
}

// Round 24
// 26.541 us; speedup vs baseline: 1.1205x; 1.0799x over previous
//
#include <hip/hip_runtime.h>

// CGP coupler, duo+quad packed, b128 8-row geometry, packed-fp32 math,
// NONTEMPORAL single-use memory traffic (ext_vector types for builtins).
//
// Structure (validated R3-R22): runs of 32 entries = segments
//   out[:, 32*ob:32*ob+32] += cg * x1[:, a:a+32] * x2[:, b:b+32]
// nseg ~ 580, nob = 280, per-ob counts c in 0..7 (avg ~2), a,b 32-aligned.
//
// R22 lesson: VALU width null -> plateau is the memory pipes. out is
// write-once, x1/x2 are read-once-per-block (no cross-block row reuse):
// all marked nontemporal (no L1/L2 allocation) so the cache serves the
// hot descriptor stream and write-back isn't polluted. Descs stay cached.
// R23 compile fix: nontemporal builtins need native/ext_vector types, not
// HIP_vector_type float4 -> use ext_vector_type(4) float throughout.

#define IN_DIM  1024
#define ROWS    8
#define NOBCAP  512
#define SKIP_OB 511u

typedef float f32x2 __attribute__((ext_vector_type(2)));
typedef float f32x4 __attribute__((ext_vector_type(4)));

// ---- prep (1 block, 1024 thr): count -> packed shuffle scan -> fill ----
__global__ __launch_bounds__(1024) void prep_kernel(
    const int* __restrict__ r1, const int* __restrict__ r2,
    const int* __restrict__ ro, const float* __restrict__ cg,
    int nseg, int nob,
    uint2* __restrict__ qdesc, uint2* __restrict__ ddesc,
    int* __restrict__ zlist, int* __restrict__ hdr)
{
    __shared__ int cntS[NOBCAP], rankS[NOBCAP];
    __shared__ int qoffS[NOBCAP], doffS[NOBCAP];
    __shared__ int wsum[8], woff[8];
    const int t = threadIdx.x;

    if (t < NOBCAP) { cntS[t] = 0; rankS[t] = 0; }
    __syncthreads();

    for (int s = t; s < nseg; s += 1024)
        atomicAdd(&cntS[ro[s << 5] >> 5], 1);
    __syncthreads();

    // packed per-ob value: q(quads)<<20 | d(is-duo)<<10 | z(is-shared)
    int c = 0;
    unsigned int pv = 0;
    if (t < NOBCAP) {
        c = (t < nob) ? cntS[t] : 0;
        const int q  = (t < nob && c >= 3) ? ((c + 3) >> 2) : 0;
        const int df = (t < nob && c <= 2) ? 1 : 0;
        const int zf = (t < nob && c > 4) ? 1 : 0;
        pv = ((unsigned int)q << 20) | ((unsigned int)df << 10) | (unsigned int)zf;
    }
    const int lane = t & 63;
    const int wid  = t >> 6;
    #pragma unroll
    for (int off = 1; off < 64; off <<= 1) {
        const unsigned int n = __shfl_up(pv, off, 64);
        if (lane >= off) pv += n;
    }
    if (t < NOBCAP && lane == 63) wsum[wid] = (int)pv;
    __syncthreads();
    if (t < 8) {
        unsigned int v = (unsigned int)wsum[t];
        const unsigned int self = v;
        #pragma unroll
        for (int off = 1; off < 8; off <<= 1) {
            const unsigned int n = __shfl_up(v, off, 64);
            if (t >= off) v += n;
        }
        woff[t] = (int)(v - self);
    }
    __syncthreads();

    if (t < NOBCAP) {
        const unsigned int incl = pv + (unsigned int)woff[wid];
        const int qi = (incl >> 20) & 1023;
        const int di = (incl >> 10) & 1023;
        const int zi = incl & 1023;
        if (t < nob) {
            if (c <= 2) {                                   // duo ob (incl empty)
                const int db = di - 1;
                doffS[t] = db;
                const unsigned int pd = ((unsigned int)t << 20) | 0x80000000u;
                for (int j = (db << 1) + c; j < ((db + 1) << 1); ++j)
                    ddesc[j] = make_uint2(pd, 0u);          // pad: cg=0
            } else {                                        // quad ob
                const int qn = (c + 3) >> 2;
                const int qb = qi - qn;
                qoffS[t] = qb;
                const unsigned int fl = (c > 4) ? 0u : 0x80000000u;
                if (c > 4) zlist[zi - 1] = t;
                const unsigned int pd = ((unsigned int)t << 20) | fl;
                for (int j = (qb << 2) + c; j < ((qb + qn) << 2); ++j)
                    qdesc[j] = make_uint2(pd, 0u);
            }
        }
        if (t == NOBCAP - 1) {
            const int nq = qi, nd = di;
            const int nqPad = (nq + 15) & ~15;              // 16 quads (1/wave)
            const int ndPad = (nd + 31) & ~31;              // 32 duos (1 pair/wave)
            const uint2 dummy = make_uint2(SKIP_OB << 20, 0u);  // terminal skipped
            for (int j = (nq << 2); j < (nqPad << 2); ++j) qdesc[j] = dummy;
            for (int j = (nd << 1); j < (ndPad << 1); ++j) ddesc[j] = dummy;
            hdr[0] = nqPad; hdr[1] = zi; hdr[2] = ndPad;
        }
    }
    __syncthreads();

    for (int s = t; s < nseg; s += 1024) {
        const int k  = s << 5;
        const int ob = ro[k] >> 5;
        const int cc = cntS[ob];
        const int rk = atomicAdd(&rankS[ob], 1);
        const unsigned int fl = (cc > 4) ? 0u : 0x80000000u;
        const uint2 v = make_uint2((unsigned int)r1[k] | ((unsigned int)r2[k] << 10)
                                   | ((unsigned int)ob << 20) | fl,
                                   __float_as_uint(cg[k]));
        if (cc <= 2) ddesc[(doffS[ob] << 1) + rk] = v;
        else         qdesc[(qoffS[ob] << 2) + rk] = v;
    }
}

// packed-fp32 accumulate: ds_read_b128 loads, v_pk_mul/v_pk_fma math
__device__ __forceinline__ void accum4(f32x2& lo, f32x2& hi,
                                       unsigned int dx, unsigned int dc,
                                       const float* xs1, const float* xs2)
{
    const float  c = __uint_as_float(dc);
    const f32x4 u = *reinterpret_cast<const f32x4*>(xs1 + (dx & 1023u));
    const f32x4 v = *reinterpret_cast<const f32x4*>(xs2 + ((dx >> 10) & 1023u));
    const f32x2 cc  = {c, c};
    const f32x2 u01 = {u.x, u.y}, u23 = {u.z, u.w};
    const f32x2 v01 = {v.x, v.y}, v23 = {v.z, v.w};
    lo += cc * (u01 * v01);      // pk_mul + pk_fma (contract)
    hi += cc * (u23 * v23);
}

__device__ __forceinline__ void terminal(float* orow, unsigned int hx,
                                         f32x2 lo, f32x2 hi)
{
    const int ob = (int)((hx >> 20) & 511u);
    if (ob == (int)SKIP_OB) return;                  // tail pad: no output
    float* p = orow + (ob << 5);
    if (hx >> 31) {
        const f32x4 st = {lo.x, lo.y, hi.x, hi.y};
        __builtin_nontemporal_store(st, reinterpret_cast<f32x4*>(p));
    } else {                                         // shared: native fadd
        unsafeAtomicAdd(p,     lo.x);
        unsafeAtomicAdd(p + 1, lo.y);
        unsafeAtomicAdd(p + 2, hi.x);
        unsafeAtomicAdd(p + 3, hi.y);
    }
}

// ---- main: block = 8 rows, 16 waves; lane = row(3b) x float4-group(3b) ----
__global__ __launch_bounds__(1024) void cgp_main(const float* __restrict__ x1,
    const float* __restrict__ x2, const uint2* __restrict__ qdesc,
    const uint2* __restrict__ ddesc, const int* __restrict__ zlist,
    const int* __restrict__ hdr, float* __restrict__ out, int out_dim)
{
    __shared__ float x1s[ROWS * IN_DIM];             // 32 KB
    __shared__ float x2s[ROWS * IN_DIM];             // 32 KB
    const int r0  = blockIdx.x * ROWS;
    const int tid = threadIdx.x;

    {
        const f32x4* p1 = reinterpret_cast<const f32x4*>(x1 + (size_t)r0 * IN_DIM);
        const f32x4* p2 = reinterpret_cast<const f32x4*>(x2 + (size_t)r0 * IN_DIM);
        f32x4* s1 = reinterpret_cast<f32x4*>(x1s);
        f32x4* s2 = reinterpret_cast<f32x4*>(x2s);
        #pragma unroll
        for (int j = tid; j < (ROWS * IN_DIM) >> 2; j += 1024) {
            s1[j] = __builtin_nontemporal_load(p1 + j);   // read-once rows
            s2[j] = __builtin_nontemporal_load(p2 + j);
        }
    }
    const int nz = hdr[1];
    for (int i = tid; i < (nz << 5); i += 1024) {    // pre-zero shared obs
        const int ob = zlist[i >> 5];
        const int ch = i & 31;
        float* p = out + (size_t)r0 * out_dim + (ob << 5) + ch;
        #pragma unroll
        for (int j = 0; j < ROWS; ++j)
            __builtin_nontemporal_store(0.f, p + j * out_dim);
    }
    __syncthreads();

    const int w  = tid >> 6;                         // wave 0..15
    const int ln = tid & 63;
    const int rr = ln >> 3;                          // row 0..7
    const int tt = ln & 7;                           // float4-channel group
    const float* xs1 = x1s + rr * IN_DIM + (tt << 2);
    const float* xs2 = x2s + rr * IN_DIM + (tt << 2);
    float* orow = out + (size_t)(r0 + rr) * out_dim + (tt << 2);

    // ---- quad loop (obs with c>=3) ----
    {
        const int qpw = hdr[0] >> 4;                 // quads per wave
        const uint2* qd = qdesc + ((size_t)(w * qpw) << 2);
        #pragma unroll 2
        for (int i = 0; i < qpw; ++i, qd += 4) {
            const uint4 A  = *reinterpret_cast<const uint4*>(qd);
            const uint4 Bq = *reinterpret_cast<const uint4*>(qd + 2);
            f32x2 lo = {0.f, 0.f}, hi = {0.f, 0.f};
            accum4(lo, hi, A.x,  A.y,  xs1, xs2);
            accum4(lo, hi, A.z,  A.w,  xs1, xs2);
            accum4(lo, hi, Bq.x, Bq.y, xs1, xs2);
            accum4(lo, hi, Bq.z, Bq.w, xs1, xs2);
            terminal(orow, A.x, lo, hi);
        }
    }

    // ---- duo-pair loop (obs with c<=2; two independent terminals) ----
    {
        const int ppw = hdr[2] >> 5;                 // duo-pairs per wave
        const uint2* dd = ddesc + ((size_t)(w * ppw) << 2);
        #pragma unroll 2
        for (int i = 0; i < ppw; ++i, dd += 4) {
            const uint4 A  = *reinterpret_cast<const uint4*>(dd);
            const uint4 Bq = *reinterpret_cast<const uint4*>(dd + 2);
            f32x2 l0 = {0.f, 0.f}, h0 = {0.f, 0.f};
            f32x2 l1 = {0.f, 0.f}, h1 = {0.f, 0.f};
            accum4(l0, h0, A.x,  A.y,  xs1, xs2);
            accum4(l0, h0, A.z,  A.w,  xs1, xs2);
            accum4(l1, h1, Bq.x, Bq.y, xs1, xs2);
            accum4(l1, h1, Bq.z, Bq.w, xs1, xs2);
            terminal(orow, A.x,  l0, h0);
            terminal(orow, Bq.x, l1, h1);
        }
    }
}

extern "C" void kernel_launch(void* const* d_in, const int* in_sizes, int n_in,
                              void* d_out, int out_size, void* d_ws, size_t ws_size,
                              hipStream_t stream)
{
    const float* x1 = (const float*)d_in[0];
    const float* x2 = (const float*)d_in[1];
    const float* cg = (const float*)d_in[2];
    const int*   r1 = (const int*)d_in[3];
    const int*   r2 = (const int*)d_in[4];
    const int*   ro = (const int*)d_in[5];
    float* out = (float*)d_out;

    const int B       = in_sizes[0] / IN_DIM;   // 2048
    const int out_dim = out_size / B;           // 8960
    const int K       = in_sizes[2];
    const int nseg    = K >> 5;                 // ~580
    const int nob     = out_dim >> 5;           // 280
    const int qcap    = nob + (nseg >> 2) + 32; // quad capacity upper bound
    const int dcap    = nob + 48;               // duo capacity upper bound

    auto align16 = [](size_t v) { return (v + 15) & ~(size_t)15; };
    char* ws = (char*)d_ws;
    uint2* qdesc = (uint2*)ws;  ws += align16((size_t)qcap * 4 * sizeof(uint2));
    uint2* ddesc = (uint2*)ws;  ws += align16((size_t)dcap * 2 * sizeof(uint2));
    int*   zlist = (int*)ws;    ws += align16((size_t)NOBCAP * sizeof(int));
    int*   hdr   = (int*)ws;

    hipLaunchKernelGGL(prep_kernel, dim3(1), dim3(1024), 0, stream,
                       r1, r2, ro, cg, nseg, nob, qdesc, ddesc, zlist, hdr);
    hipLaunchKernelGGL(cgp_main, dim3(B / ROWS), dim3(1024), 0, stream,
                       x1, x2, qdesc, ddesc, zlist, hdr, out, out_dim);
}

// Round 25
// 26.394 us; speedup vs baseline: 1.1267x; 1.0056x over previous
//
#include <hip/hip_runtime.h>

// CGP coupler, ONE-DISPATCH fused form with register-staged overlap.
//
// Structure (validated R3-R24): runs of 32 entries = segments
//   out[:, 32*ob:32*ob+32] += cg * x1[:, a:a+32] * x2[:, b:b+32]
// nseg ~ 580 (<=1024), nob = 280, counts c in 0..7 (avg ~2), 32-aligned.
//
// R24 (26.5 us): NT stores/loads -7%. Remaining addressable: prep dispatch
// + launch gap (~5.5 us) and serial staging (~2.5 us). This kernel:
//  - issues prep's global loads (1 round) THEN the 64 KB row staging as
//    REGISTER NT loads; prep value-waits leave staging in flight (FIFO)
//  - prep-internal barriers are lgkm-only (raw s_barrier + waitcnt, HK
//    pattern) so no vmcnt drain until regs->LDS write
//  - descriptors built in LDS; compute = R24 loops with ds-read descs
//  - NT terminal stores; full vmcnt+lgkm drain barrier before compute.

#define IN_DIM  1024
#define ROWS    8
#define NOBCAP  512
#define SKIP_OB 511u
#define QSLOTS  1024
#define DSLOTS  640

typedef float f32x2 __attribute__((ext_vector_type(2)));
typedef float f32x4 __attribute__((ext_vector_type(4)));

// lgkm-only barrier: orders LDS ops across the block without draining vmem
#define BAR_LDS() do { asm volatile("s_waitcnt lgkmcnt(0)" ::: "memory"); \
                       __builtin_amdgcn_s_barrier(); } while (0)
// full drain barrier (global stores/loads + LDS visible)
#define BAR_ALL() do { asm volatile("s_waitcnt vmcnt(0) lgkmcnt(0)" ::: "memory"); \
                       __builtin_amdgcn_s_barrier(); } while (0)

__device__ __forceinline__ void accum4(f32x2& lo, f32x2& hi,
                                       unsigned int dx, unsigned int dc,
                                       const float* xs1, const float* xs2)
{
    const float c = __uint_as_float(dc);
    const f32x4 u = *reinterpret_cast<const f32x4*>(xs1 + (dx & 1023u));
    const f32x4 v = *reinterpret_cast<const f32x4*>(xs2 + ((dx >> 10) & 1023u));
    const f32x2 cc  = {c, c};
    const f32x2 u01 = {u.x, u.y}, u23 = {u.z, u.w};
    const f32x2 v01 = {v.x, v.y}, v23 = {v.z, v.w};
    lo += cc * (u01 * v01);      // v_pk_mul + v_pk_fma
    hi += cc * (u23 * v23);
}

__device__ __forceinline__ void terminal(float* orow, unsigned int hx,
                                         f32x2 lo, f32x2 hi)
{
    const int ob = (int)((hx >> 20) & 511u);
    if (ob == (int)SKIP_OB) return;                  // tail pad: no output
    float* p = orow + (ob << 5);
    if (hx >> 31) {
        const f32x4 st = {lo.x, lo.y, hi.x, hi.y};
        __builtin_nontemporal_store(st, reinterpret_cast<f32x4*>(p));
    } else {                                         // shared: native fadd
        unsafeAtomicAdd(p,     lo.x);
        unsafeAtomicAdd(p + 1, lo.y);
        unsafeAtomicAdd(p + 2, hi.x);
        unsafeAtomicAdd(p + 3, hi.y);
    }
}

__global__ __launch_bounds__(1024) void cgp_fused(
    const float* __restrict__ x1, const float* __restrict__ x2,
    const int* __restrict__ r1, const int* __restrict__ r2,
    const int* __restrict__ ro, const float* __restrict__ cg,
    int nseg, int nob, float* __restrict__ out, int out_dim)
{
    __shared__ __align__(16) float x1s[ROWS * IN_DIM];   // 32 KB
    __shared__ __align__(16) float x2s[ROWS * IN_DIM];   // 32 KB
    __shared__ __align__(16) uint2 qdescL[QSLOTS];       // 8 KB
    __shared__ __align__(16) uint2 ddescL[DSLOTS];       // 5 KB
    __shared__ int cntS[NOBCAP], rankS[NOBCAP];          // 4 KB
    __shared__ int qoffS[NOBCAP], doffS[NOBCAP];         // 4 KB
    __shared__ int wsum[8], woff[8];
    __shared__ int zlistL[128];
    __shared__ int hdrL[4];

    const int t  = threadIdx.x;                          // 0..1023
    const int r0 = blockIdx.x * ROWS;

    // ---- zero counters first (LDS only, no loads yet) ----
    if (t < NOBCAP) { cntS[t] = 0; rankS[t] = 0; }

    // ---- prep global loads: ONE round covers nseg <= 1024 ----
    int roV = 0, r1V = 0, r2V = 0; float cgV = 0.f;
    if (t < nseg) {
        const int k = t << 5;
        roV = ro[k]; r1V = r1[k]; r2V = r2[k]; cgV = cg[k];
    }

    // ---- staging loads into REGISTERS (issued after prep loads; their
    //      drain is deferred to the regs->LDS write below) ----
    const f32x4* p1 = reinterpret_cast<const f32x4*>(x1 + (size_t)r0 * IN_DIM);
    const f32x4* p2 = reinterpret_cast<const f32x4*>(x2 + (size_t)r0 * IN_DIM);
    const f32x4 sA = __builtin_nontemporal_load(p1 + t);
    const f32x4 sB = __builtin_nontemporal_load(p1 + t + 1024);
    const f32x4 sC = __builtin_nontemporal_load(p2 + t);
    const f32x4 sD = __builtin_nontemporal_load(p2 + t + 1024);

    BAR_LDS();                                           // zeros visible

    // ---- count (LDS int atomics; waits only on prep loads) ----
    for (int s = t; s < nseg; s += 1024)
        atomicAdd(&cntS[((s == t) ? roV : ro[s << 5]) >> 5], 1);
    BAR_LDS();

    // ---- packed shuffle scan over 512 ob slots (threads 0..511) ----
    int c = 0; unsigned int pv = 0;
    if (t < NOBCAP) {
        c = (t < nob) ? cntS[t] : 0;
        const int q  = (t < nob && c >= 3) ? ((c + 3) >> 2) : 0;
        const int df = (t < nob && c <= 2) ? 1 : 0;
        const int zf = (t < nob && c > 4) ? 1 : 0;
        pv = ((unsigned int)q << 20) | ((unsigned int)df << 10) | (unsigned int)zf;
    }
    const int lane = t & 63, wid = t >> 6;
    #pragma unroll
    for (int off = 1; off < 64; off <<= 1) {
        const unsigned int n = __shfl_up(pv, off, 64);
        if (lane >= off) pv += n;
    }
    if (t < NOBCAP && lane == 63) wsum[wid] = (int)pv;
    BAR_LDS();
    if (t < 8) {
        unsigned int v = (unsigned int)wsum[t];
        const unsigned int self = v;
        #pragma unroll
        for (int off = 1; off < 8; off <<= 1) {
            const unsigned int n = __shfl_up(v, off, 64);
            if (t >= off) v += n;
        }
        woff[t] = (int)(v - self);
    }
    BAR_LDS();

    // ---- per-ob offsets, pads, hdr, zlist ----
    if (t < NOBCAP) {
        const unsigned int incl = pv + (unsigned int)woff[wid];
        const int qi = (incl >> 20) & 1023;
        const int di = (incl >> 10) & 1023;
        const int zi = incl & 1023;
        if (t < nob) {
            if (c <= 2) {                                // duo ob (incl empty)
                const int db = di - 1;
                doffS[t] = db;
                const unsigned int pd = ((unsigned int)t << 20) | 0x80000000u;
                for (int j = (db << 1) + c; j < ((db + 1) << 1); ++j)
                    ddescL[j] = make_uint2(pd, 0u);      // pad: cg=0
            } else {                                     // quad ob
                const int qn = (c + 3) >> 2;
                const int qb = qi - qn;
                qoffS[t] = qb;
                const unsigned int fl = (c > 4) ? 0u : 0x80000000u;
                if (c > 4) zlistL[zi - 1] = t;
                const unsigned int pd = ((unsigned int)t << 20) | fl;
                for (int j = (qb << 2) + c; j < ((qb + qn) << 2); ++j)
                    qdescL[j] = make_uint2(pd, 0u);
            }
        }
        if (t == NOBCAP - 1) {
            const int nq = qi, nd = di;
            const int nqPad = (nq + 15) & ~15;           // 16 quads (1/wave)
            const int ndPad = (nd + 31) & ~31;           // 32 duos (pair/wave)
            const uint2 dummy = make_uint2(SKIP_OB << 20, 0u);
            for (int j = (nq << 2); j < (nqPad << 2); ++j) qdescL[j] = dummy;
            for (int j = (nd << 1); j < (ndPad << 1); ++j) ddescL[j] = dummy;
            hdrL[0] = nqPad; hdrL[1] = zi; hdrL[2] = ndPad;
        }
    }
    BAR_LDS();

    // ---- fill real descriptors into LDS (values preloaded) ----
    for (int s = t; s < nseg; s += 1024) {
        int ob, rv1, rv2; float cgx;
        if (s == t) { ob = roV >> 5; rv1 = r1V; rv2 = r2V; cgx = cgV; }
        else { const int k = s << 5; ob = ro[k] >> 5; rv1 = r1[k]; rv2 = r2[k]; cgx = cg[k]; }
        const int cc = cntS[ob];
        const int rk = atomicAdd(&rankS[ob], 1);
        const unsigned int fl = (cc > 4) ? 0u : 0x80000000u;
        const uint2 v = make_uint2((unsigned int)rv1 | ((unsigned int)rv2 << 10)
                                   | ((unsigned int)ob << 20) | fl,
                                   __float_as_uint(cgx));
        if (cc <= 2) ddescL[(doffS[ob] << 1) + rk] = v;
        else         qdescL[(qoffS[ob] << 2) + rk] = v;
    }

    // ---- regs -> LDS (staging vmem drains here via value deps) ----
    {
        f32x4* s1 = reinterpret_cast<f32x4*>(x1s);
        f32x4* s2 = reinterpret_cast<f32x4*>(x2s);
        s1[t] = sA; s1[t + 1024] = sB;
        s2[t] = sC; s2[t + 1024] = sD;
    }

    // ---- pre-zero shared obs (needs hdr/zlist: ordered by prior BAR_LDS) ----
    const int nz = hdrL[1];
    for (int i = t; i < (nz << 5); i += 1024) {
        const int ob = zlistL[i >> 5], ch = i & 31;
        float* p = out + (size_t)r0 * out_dim + (ob << 5) + ch;
        #pragma unroll
        for (int j = 0; j < ROWS; ++j)
            __builtin_nontemporal_store(0.f, p + j * out_dim);
    }
    BAR_ALL();   // zeros + LDS rows + descs all visible before compute

    // ---- compute (R24 loops, descriptors from LDS) ----
    const int w  = t >> 6;                               // wave 0..15
    const int ln = t & 63;
    const int rr = ln >> 3;                              // row 0..7
    const int tt = ln & 7;                               // float4-group
    const float* xs1 = x1s + rr * IN_DIM + (tt << 2);
    const float* xs2 = x2s + rr * IN_DIM + (tt << 2);
    float* orow = out + (size_t)(r0 + rr) * out_dim + (tt << 2);

    // quad loop (obs with c>=3)
    {
        const int qpw = hdrL[0] >> 4;
        const uint2* qd = qdescL + ((size_t)(w * qpw) << 2);
        #pragma unroll 2
        for (int i = 0; i < qpw; ++i, qd += 4) {
            const uint4 A  = *reinterpret_cast<const uint4*>(qd);
            const uint4 Bq = *reinterpret_cast<const uint4*>(qd + 2);
            f32x2 lo = {0.f, 0.f}, hi = {0.f, 0.f};
            accum4(lo, hi, A.x,  A.y,  xs1, xs2);
            accum4(lo, hi, A.z,  A.w,  xs1, xs2);
            accum4(lo, hi, Bq.x, Bq.y, xs1, xs2);
            accum4(lo, hi, Bq.z, Bq.w, xs1, xs2);
            terminal(orow, A.x, lo, hi);
        }
    }
    // duo-pair loop (obs with c<=2)
    {
        const int ppw = hdrL[2] >> 5;
        const uint2* dd = ddescL + ((size_t)(w * ppw) << 2);
        #pragma unroll 2
        for (int i = 0; i < ppw; ++i, dd += 4) {
            const uint4 A  = *reinterpret_cast<const uint4*>(dd);
            const uint4 Bq = *reinterpret_cast<const uint4*>(dd + 2);
            f32x2 l0 = {0.f, 0.f}, h0 = {0.f, 0.f};
            f32x2 l1 = {0.f, 0.f}, h1 = {0.f, 0.f};
            accum4(l0, h0, A.x,  A.y,  xs1, xs2);
            accum4(l0, h0, A.z,  A.w,  xs1, xs2);
            accum4(l1, h1, Bq.x, Bq.y, xs1, xs2);
            accum4(l1, h1, Bq.z, Bq.w, xs1, xs2);
            terminal(orow, A.x,  l0, h0);
            terminal(orow, Bq.x, l1, h1);
        }
    }
}

extern "C" void kernel_launch(void* const* d_in, const int* in_sizes, int n_in,
                              void* d_out, int out_size, void* d_ws, size_t ws_size,
                              hipStream_t stream)
{
    const float* x1 = (const float*)d_in[0];
    const float* x2 = (const float*)d_in[1];
    const float* cg = (const float*)d_in[2];
    const int*   r1 = (const int*)d_in[3];
    const int*   r2 = (const int*)d_in[4];
    const int*   ro = (const int*)d_in[5];
    float* out = (float*)d_out;

    const int B       = in_sizes[0] / IN_DIM;   // 2048
    const int out_dim = out_size / B;           // 8960
    const int K       = in_sizes[2];
    const int nseg    = K >> 5;                 // ~580 (<= 1024)
    const int nob     = out_dim >> 5;           // 280

    hipLaunchKernelGGL(cgp_fused, dim3(B / ROWS), dim3(1024), 0, stream,
                       x1, x2, r1, r2, ro, cg, nseg, nob, out, out_dim);
}